// Round 2
// baseline (864.686 us; speedup 1.0000x reference)
//
#include <hip/hip_runtime.h>
#include <math.h>

// Problem constants (fixed by reference: B=8, Cl=128, Ch=64, Hl=Wl=96, Hh=Wh=192, CROSS=12)
#define NB 8
#define CL 128
#define CH 64
#define HL 96
#define WL 96
#define PL (HL*WL)          // 9216
#define HH 192
#define WH 192
#define PH (HH*WH)          // 36864
#define NS 144              // CROSS*CROSS
#define BN_S 0.9999950000374997f   // 1/sqrt(1+1e-5)
#define INV12 (1.0f/12.0f)         // S^-0.5

__device__ __forceinline__ float gelu_exact(float x){
    return 0.5f*x*(1.0f + erff(x*0.7071067811865475f));
}

// ---------------- K1: x_l2 = x_l + mlp_l(x_l), fused 2x (128x128) conv + GELU ----------------
__global__ __launch_bounds__(256) void k_mlp_l(
    const float* __restrict__ xl, const float* __restrict__ w1, const float* __restrict__ b1,
    const float* __restrict__ w2, const float* __restrict__ b2, float* __restrict__ xl2)
{
    __shared__ float Xs[CL*64];
    __shared__ float Hs[CL*64];
    const int tid = threadIdx.x;
    const int b   = blockIdx.x / (PL/64);
    const int hw0 = (blockIdx.x % (PL/64)) * 64;
    const float* xb = xl + (size_t)b*CL*PL + hw0;
    #pragma unroll
    for (int i=0;i<32;i++){
        int idx = i*256+tid;
        Xs[idx] = xb[(size_t)(idx>>6)*PL + (idx&63)];
    }
    __syncthreads();
    const int o0 = (tid>>4)*8;       // 16 groups x 8 out-ch
    const int p0 = (tid&15)*4;       // 16 groups x 4 px
    float acc[8][4];
    #pragma unroll
    for (int k=0;k<8;k++){
        float v = b1[o0+k];
        acc[k][0]=v; acc[k][1]=v; acc[k][2]=v; acc[k][3]=v;
    }
    #pragma unroll 4
    for (int c=0;c<CL;c++){
        float4 xv = *(const float4*)&Xs[c*64+p0];
        #pragma unroll
        for (int k=0;k<8;k++){
            float w = w1[(o0+k)*CL + c];
            acc[k][0]+=w*xv.x; acc[k][1]+=w*xv.y; acc[k][2]+=w*xv.z; acc[k][3]+=w*xv.w;
        }
    }
    #pragma unroll
    for (int k=0;k<8;k++){
        float4 h = make_float4(gelu_exact(acc[k][0]), gelu_exact(acc[k][1]),
                               gelu_exact(acc[k][2]), gelu_exact(acc[k][3]));
        *(float4*)&Hs[(o0+k)*64+p0] = h;
    }
    __syncthreads();
    #pragma unroll
    for (int k=0;k<8;k++){
        float v = b2[o0+k];
        acc[k][0]=v; acc[k][1]=v; acc[k][2]=v; acc[k][3]=v;
    }
    #pragma unroll 4
    for (int c=0;c<CL;c++){
        float4 hv = *(const float4*)&Hs[c*64+p0];
        #pragma unroll
        for (int k=0;k<8;k++){
            float w = w2[(o0+k)*CL + c];
            acc[k][0]+=w*hv.x; acc[k][1]+=w*hv.y; acc[k][2]+=w*hv.z; acc[k][3]+=w*hv.w;
        }
    }
    float* yb = xl2 + (size_t)b*CL*PL + hw0;
    #pragma unroll
    for (int k=0;k<8;k++){
        float4 r = *(const float4*)&Xs[(o0+k)*64+p0];
        float4 y = make_float4(acc[k][0]+r.x, acc[k][1]+r.y, acc[k][2]+r.z, acc[k][3]+r.w);
        *(float4*)&yb[(size_t)(o0+k)*PL + p0] = y;
    }
}

// ---------------- K2: xc = relu(bn(conv1x1(x_l2, conv_w))), BN folded as post-scale ----------------
__global__ __launch_bounds__(256) void k_conv_l(
    const float* __restrict__ xl2, const float* __restrict__ cw,
    const float* __restrict__ bng, const float* __restrict__ bnb, float* __restrict__ xc)
{
    __shared__ float Xs[CL*64];
    const int tid = threadIdx.x;
    const int b   = blockIdx.x / (PL/64);
    const int hw0 = (blockIdx.x % (PL/64)) * 64;
    const float* xb = xl2 + (size_t)b*CL*PL + hw0;
    #pragma unroll
    for (int i=0;i<32;i++){
        int idx = i*256+tid;
        Xs[idx] = xb[(size_t)(idx>>6)*PL + (idx&63)];
    }
    __syncthreads();
    const int o0 = (tid>>4)*4;       // 16 groups x 4 out-ch (64 total)
    const int p0 = (tid&15)*4;
    float acc[4][4] = {};
    #pragma unroll 4
    for (int c=0;c<CL;c++){
        float4 xv = *(const float4*)&Xs[c*64+p0];
        #pragma unroll
        for (int k=0;k<4;k++){
            float w = cw[(o0+k)*CL + c];
            acc[k][0]+=w*xv.x; acc[k][1]+=w*xv.y; acc[k][2]+=w*xv.z; acc[k][3]+=w*xv.w;
        }
    }
    float* yb = xc + (size_t)b*CH*PL + hw0;
    #pragma unroll
    for (int k=0;k<4;k++){
        float sc = bng[o0+k]*BN_S, bb = bnb[o0+k];
        float4 y = make_float4(fmaxf(sc*acc[k][0]+bb, 0.f), fmaxf(sc*acc[k][1]+bb, 0.f),
                               fmaxf(sc*acc[k][2]+bb, 0.f), fmaxf(sc*acc[k][3]+bb, 0.f));
        *(float4*)&yb[(size_t)(o0+k)*PL + p0] = y;
    }
}

// ---------------- K3: x_h2 = x_h + bilinear_up2x(xc)  (half-pixel centers, edge clamp) ----------------
__global__ __launch_bounds__(256) void k_upsample_add(
    const float* __restrict__ xc, const float* __restrict__ xh, float* __restrict__ xh2)
{
    int gid = blockIdx.x*256 + threadIdx.x;
    int x = gid % WH;
    int r = gid / WH;
    int y = r % HH;
    int plane = r / HH;            // b*CH + c
    const float* s = xc + (size_t)plane*PL;
    int lx = (x>>1) - ((x&1)^1);               // even: x/2-1, odd: x/2
    float fx = (x&1) ? 0.25f : 0.75f;          // weight of hi
    int x0i = lx<0?0:lx; int x1i = (lx+1>WL-1)?(WL-1):(lx+1);
    int ly = (y>>1) - ((y&1)^1);
    float fy = (y&1) ? 0.25f : 0.75f;
    int y0i = ly<0?0:ly; int y1i = (ly+1>HL-1)?(HL-1):(ly+1);
    float v00 = s[y0i*WL+x0i], v01 = s[y0i*WL+x1i];
    float v10 = s[y1i*WL+x0i], v11 = s[y1i*WL+x1i];
    float top = v00 + fx*(v01-v00);
    float bot = v10 + fx*(v11-v10);
    float up  = top + fy*(bot-top);
    xh2[gid] = xh[gid] + up;
}

// ---------------- K4a: pooled[b,c,s] = max_{8x8}( bn_kv(x_l2) ), bn applied per element ----------------
__global__ __launch_bounds__(192) void k_pool(
    const float* __restrict__ xl2, const float* __restrict__ g, const float* __restrict__ bta,
    float* __restrict__ pooled)
{
    const int plane = blockIdx.x;      // b*CL + c
    const int tid = threadIdx.x;
    if (tid >= NS) return;
    const int c = plane & (CL-1);
    const float sc = g[c]*BN_S;
    const float tc = bta[c];
    const int i = tid/12, j = tid%12;
    const float* base = xl2 + (size_t)plane*PL + (size_t)i*8*WL + j*8;
    float m = -3.4e38f;
    #pragma unroll
    for (int dy=0;dy<8;dy++){
        const float* rr = base + dy*WL;
        #pragma unroll
        for (int dx=0;dx<8;dx++){
            m = fmaxf(m, sc*rr[dx]+tc);
        }
    }
    pooled[(size_t)plane*NS + tid] = m;
}

// ---------------- K4b: kv = conv1x1(pooled, kv_w)+kv_b; split K (with norm-bn + 1/12 folded) and V ----
// keg[b][s][ch] = kv[b][ch][s] * norm_g[ch]*BN_S/12 ; biasg[b][s] = sum_ch kv[b][ch][s]*norm_b[ch]/12
// vg [b][s][ch] = kv[b][64+ch][s]
__global__ __launch_bounds__(512) void k_kv(
    const float* __restrict__ pooled, const float* __restrict__ kvw, const float* __restrict__ kvb,
    const float* __restrict__ ng, const float* __restrict__ nb,
    float* __restrict__ keg, float* __restrict__ vg, float* __restrict__ biasg)
{
    const int b = blockIdx.x;
    const int tid = threadIdx.x;
    const int o  = tid>>2;             // 0..127
    const int sq = (tid&3)*36;         // 4 s-quarters
    const float* P = pooled + (size_t)b*CL*NS + sq;
    float acc[36];
    float bb = kvb[o];
    #pragma unroll
    for (int s=0;s<36;s++) acc[s] = bb;
    for (int c=0;c<CL;c++){
        float w = kvw[o*CL+c];
        const float* Pr = P + c*NS;
        #pragma unroll
        for (int s=0;s<36;s++) acc[s] += w*Pr[s];
    }
    if (o < CH){
        float sn = ng[o]*(BN_S*INV12);
        float tn = nb[o]*INV12;
        #pragma unroll
        for (int s=0;s<36;s++){
            int ss = sq+s;
            keg[((size_t)b*NS+ss)*CH + o] = acc[s]*sn;
            atomicAdd(&biasg[b*NS+ss], acc[s]*tn);
        }
    } else {
        const int ch = o-CH;
        #pragma unroll
        for (int s=0;s<36;s++)
            vg[((size_t)b*NS+(sq+s))*CH + ch] = acc[s];
    }
}

// ---------------- K5: cross-attention per 32-pixel tile; writes x_h3 = x_h2 + attn_out to d_out ------
__global__ __launch_bounds__(256) void k_attn(
    const float* __restrict__ xh2, const float* __restrict__ keg, const float* __restrict__ vg,
    const float* __restrict__ biasg, float* __restrict__ out)
{
    __shared__ float KV[NS*65];    // Ke then (reused) V, row-padded to 65 floats
    __shared__ float Xs[CH*32];
    __shared__ float A[NS*32];
    __shared__ float biasS[NS];
    const int tid = threadIdx.x;
    const int b   = blockIdx.x / (PH/32);
    const int hw0 = (blockIdx.x % (PH/32)) * 32;
    const float* xb = xh2 + (size_t)b*CH*PH + hw0;
    #pragma unroll
    for (int i=0;i<8;i++){
        int idx = i*256+tid;
        Xs[idx] = xb[(size_t)(idx>>5)*PH + (idx&31)];
    }
    const float* keb = keg + (size_t)b*NS*CH;
    #pragma unroll
    for (int i=0;i<36;i++){
        int idx = i*256+tid;
        KV[(idx>>6)*65 + (idx&63)] = keb[idx];
    }
    if (tid < NS) biasS[tid] = biasg[b*NS+tid];
    __syncthreads();
    { // scores: A[s][p] = bias[s] + sum_ch Ke[s][ch]*x[ch][p]
        const int s0 = (tid>>4)*9;     // 16 groups x 9 s
        const int p0 = (tid&15)*2;     // 16 groups x 2 px
        float acc[9][2];
        #pragma unroll
        for (int k=0;k<9;k++){ float v = biasS[s0+k]; acc[k][0]=v; acc[k][1]=v; }
        for (int c=0;c<CH;c++){
            float x0v = Xs[c*32+p0], x1v = Xs[c*32+p0+1];
            #pragma unroll
            for (int k=0;k<9;k++){
                float kw = KV[(s0+k)*65 + c];
                acc[k][0] += kw*x0v; acc[k][1] += kw*x1v;
            }
        }
        #pragma unroll
        for (int k=0;k<9;k++){
            A[(s0+k)*32+p0]   = acc[k][0];
            A[(s0+k)*32+p0+1] = acc[k][1];
        }
    }
    __syncthreads();
    // softmax (threads 0..31, one pixel each) runs concurrently with V staging (threads 64..255)
    if (tid < 32){
        const int p = tid;
        float m = -3.4e38f;
        for (int s=0;s<NS;s++) m = fmaxf(m, A[s*32+p]);
        float sum = 0.f;
        for (int s=0;s<NS;s++){ float e = __expf(A[s*32+p]-m); A[s*32+p]=e; sum += e; }
        float rs = 1.f/sum;
        for (int s=0;s<NS;s++) A[s*32+p] *= rs;
    } else if (tid >= 64){
        const float* vb = vg + (size_t)b*NS*CH;
        const int t = tid - 64;        // 192 stagers
        #pragma unroll
        for (int i=0;i<48;i++){
            int idx = i*192+t;
            KV[(idx>>6)*65 + (idx&63)] = vb[idx];
        }
    }
    __syncthreads();
    { // out: O[ch][p] = sum_s V[s][ch]*P[s][p]; write residual-added to d_out
        const int ch0 = (tid>>3)*2;    // 32 groups x 2 ch
        const int p0  = (tid&7)*4;     // 8 groups x 4 px
        float oa0[4] = {0,0,0,0}, oa1[4] = {0,0,0,0};
        for (int s=0;s<NS;s++){
            float4 av = *(const float4*)&A[s*32+p0];
            float v0 = KV[s*65+ch0], v1 = KV[s*65+ch0+1];
            oa0[0]+=v0*av.x; oa0[1]+=v0*av.y; oa0[2]+=v0*av.z; oa0[3]+=v0*av.w;
            oa1[0]+=v1*av.x; oa1[1]+=v1*av.y; oa1[2]+=v1*av.z; oa1[3]+=v1*av.w;
        }
        size_t base0 = (size_t)b*CH*PH + (size_t)ch0*PH + hw0 + p0;
        float4 r0 = *(const float4*)&xh2[base0];
        *(float4*)&out[base0] = make_float4(r0.x+oa0[0], r0.y+oa0[1], r0.z+oa0[2], r0.w+oa0[3]);
        size_t base1 = base0 + PH;
        float4 r1 = *(const float4*)&xh2[base1];
        *(float4*)&out[base1] = make_float4(r1.x+oa1[0], r1.y+oa1[1], r1.z+oa1[2], r1.w+oa1[3]);
    }
}

// ---------------- K6: d_out = d_out + mlp_h(d_out), in-place per 64-px tile ----------------
__global__ __launch_bounds__(256) void k_mlp_h(
    float* __restrict__ xh, const float* __restrict__ w1, const float* __restrict__ b1,
    const float* __restrict__ w2, const float* __restrict__ b2)
{
    __shared__ float Xs[CH*64];
    __shared__ float Hs[CH*64];
    const int tid = threadIdx.x;
    const int b   = blockIdx.x / (PH/64);
    const int hw0 = (blockIdx.x % (PH/64)) * 64;
    float* xb = xh + (size_t)b*CH*PH + hw0;
    #pragma unroll
    for (int i=0;i<16;i++){
        int idx = i*256+tid;
        Xs[idx] = xb[(size_t)(idx>>6)*PH + (idx&63)];
    }
    __syncthreads();
    const int o0 = (tid>>4)*4;
    const int p0 = (tid&15)*4;
    float acc[4][4];
    #pragma unroll
    for (int k=0;k<4;k++){ float v=b1[o0+k]; acc[k][0]=v;acc[k][1]=v;acc[k][2]=v;acc[k][3]=v; }
    #pragma unroll 4
    for (int c=0;c<CH;c++){
        float4 xv = *(const float4*)&Xs[c*64+p0];
        #pragma unroll
        for (int k=0;k<4;k++){
            float w = w1[(o0+k)*CH+c];
            acc[k][0]+=w*xv.x; acc[k][1]+=w*xv.y; acc[k][2]+=w*xv.z; acc[k][3]+=w*xv.w;
        }
    }
    #pragma unroll
    for (int k=0;k<4;k++){
        float4 h = make_float4(gelu_exact(acc[k][0]),gelu_exact(acc[k][1]),
                               gelu_exact(acc[k][2]),gelu_exact(acc[k][3]));
        *(float4*)&Hs[(o0+k)*64+p0] = h;
    }
    __syncthreads();
    #pragma unroll
    for (int k=0;k<4;k++){ float v=b2[o0+k]; acc[k][0]=v;acc[k][1]=v;acc[k][2]=v;acc[k][3]=v; }
    #pragma unroll 4
    for (int c=0;c<CH;c++){
        float4 hv = *(const float4*)&Hs[c*64+p0];
        #pragma unroll
        for (int k=0;k<4;k++){
            float w = w2[(o0+k)*CH+c];
            acc[k][0]+=w*hv.x; acc[k][1]+=w*hv.y; acc[k][2]+=w*hv.z; acc[k][3]+=w*hv.w;
        }
    }
    #pragma unroll
    for (int k=0;k<4;k++){
        float4 r = *(const float4*)&Xs[(o0+k)*64+p0];
        float4 y = make_float4(acc[k][0]+r.x, acc[k][1]+r.y, acc[k][2]+r.z, acc[k][3]+r.w);
        *(float4*)&xb[(size_t)(o0+k)*PH + p0] = y;
    }
}

extern "C" void kernel_launch(void* const* d_in, const int* in_sizes, int n_in,
                              void* d_out, int out_size, void* d_ws, size_t ws_size,
                              hipStream_t stream)
{
    const float* xl    = (const float*)d_in[0];
    const float* xh    = (const float*)d_in[1];
    const float* ml_w1 = (const float*)d_in[2];
    const float* ml_b1 = (const float*)d_in[3];
    const float* ml_w2 = (const float*)d_in[4];
    const float* ml_b2 = (const float*)d_in[5];
    const float* cw    = (const float*)d_in[6];
    const float* cbg   = (const float*)d_in[7];
    const float* cbb   = (const float*)d_in[8];
    const float* kbg   = (const float*)d_in[9];
    const float* kbb   = (const float*)d_in[10];
    const float* kvw   = (const float*)d_in[11];
    const float* kvb   = (const float*)d_in[12];
    const float* ng    = (const float*)d_in[13];
    const float* nb    = (const float*)d_in[14];
    const float* mh_w1 = (const float*)d_in[15];
    const float* mh_b1 = (const float*)d_in[16];
    const float* mh_w2 = (const float*)d_in[17];
    const float* mh_b2 = (const float*)d_in[18];
    float* out = (float*)d_out;

    // workspace layout (floats): ~133.3 MB total
    float* ws     = (float*)d_ws;
    float* xl2    = ws;                          // NB*CL*PL   = 9437184
    float* xc     = xl2    + (size_t)NB*CL*PL;   // NB*CH*PL   = 4718592
    float* xh2    = xc     + (size_t)NB*CH*PL;   // NB*CH*PH   = 18874368
    float* pooled = xh2    + (size_t)NB*CH*PH;   // NB*CL*NS   = 147456
    float* keg    = pooled + (size_t)NB*CL*NS;   // NB*NS*CH   = 73728
    float* vg     = keg    + (size_t)NB*NS*CH;   // NB*NS*CH   = 73728
    float* biasg  = vg     + (size_t)NB*NS*CH;   // NB*NS      = 1152

    k_mlp_l<<<dim3(NB*PL/64), dim3(256), 0, stream>>>(xl, ml_w1, ml_b1, ml_w2, ml_b2, xl2);
    k_conv_l<<<dim3(NB*PL/64), dim3(256), 0, stream>>>(xl2, cw, cbg, cbb, xc);
    k_upsample_add<<<dim3((NB*CH*PH)/256), dim3(256), 0, stream>>>(xc, xh, xh2);
    k_pool<<<dim3(NB*CL), dim3(192), 0, stream>>>(xl2, kbg, kbb, pooled);
    hipMemsetAsync(biasg, 0, (size_t)NB*NS*sizeof(float), stream);
    k_kv<<<dim3(NB), dim3(512), 0, stream>>>(pooled, kvw, kvb, ng, nb, keg, vg, biasg);
    k_attn<<<dim3(NB*PH/32), dim3(256), 0, stream>>>(xh2, keg, vg, biasg, out);
    k_mlp_h<<<dim3(NB*PH/64), dim3(256), 0, stream>>>(out, mh_w1, mh_b1, mh_w2, mh_b2);
}

// Round 3
// 504.567 us; speedup vs baseline: 1.7137x; 1.7137x over previous
//
#include <hip/hip_runtime.h>
#include <math.h>

// Problem constants (fixed by reference: B=8, Cl=128, Ch=64, Hl=Wl=96, Hh=Wh=192, CROSS=12)
#define NB 8
#define CL 128
#define CH 64
#define HL 96
#define WL 96
#define PL (HL*WL)          // 9216
#define HH 192
#define WH 192
#define PH (HH*WH)          // 36864
#define NS 144              // CROSS*CROSS
#define BN_S 0.9999950000374997f   // 1/sqrt(1+1e-5)
#define INV12 (1.0f/12.0f)         // S^-0.5

typedef __attribute__((ext_vector_type(8))) short bf16x8;
typedef __attribute__((ext_vector_type(4))) float f32x4;
#define MFMA16(a,b,c) __builtin_amdgcn_mfma_f32_16x16x32_bf16(a,b,c,0,0,0)

__device__ __forceinline__ float gelu_exact(float x){
    return 0.5f*x*(1.0f + erff(x*0.7071067811865475f));
}
__device__ __forceinline__ short f2bf(float f){
    union { float f; unsigned u; } v; v.f = f;
    unsigned r = v.u + 0x7FFFu + ((v.u >> 16) & 1u);   // round-nearest-even
    return (short)(r >> 16);
}

// ---------------- K1: x_l2 = x_l + mlp_l(x_l)  [MFMA bf16, 64 px/block, 4 waves x 16 px] ----------
// W tiles: [o][c] stride 136 shorts; activation tiles transposed [p][c] stride 136.
__global__ __launch_bounds__(256) void k_mlp_l(
    const float* __restrict__ xl, const float* __restrict__ w1, const float* __restrict__ b1,
    const float* __restrict__ w2, const float* __restrict__ b2, float* __restrict__ xl2)
{
    __shared__ short Wb[128*136];   // W1 then W2
    __shared__ short Xb[64*136];    // Xt then Ht
    __shared__ float bS[256];       // b1 | b2
    const int tid = threadIdx.x;
    const int b   = blockIdx.x / (PL/64);
    const int hw0 = (blockIdx.x % (PL/64)) * 64;
    const float* xb = xl + (size_t)b*CL*PL + hw0;
    #pragma unroll
    for (int i=0;i<64;i++){ int idx=i*256+tid; Wb[(idx>>7)*136 + (idx&127)] = f2bf(w1[idx]); }
    #pragma unroll
    for (int i=0;i<32;i++){ int idx=i*256+tid; int c=idx>>6, p=idx&63;
        Xb[p*136+c] = f2bf(xb[(size_t)c*PL + p]); }
    if (tid < 128) bS[tid] = b1[tid]; else bS[tid] = b2[tid-128];
    __syncthreads();
    const int w = tid>>6, lane = tid&63, l16 = lane&15, q = lane>>4;
    const int pw = w*16;
    float hv[8][4];
    #pragma unroll
    for (int mt=0; mt<8; mt++){
        f32x4 acc = {0.f,0.f,0.f,0.f};
        #pragma unroll
        for (int k=0;k<4;k++){
            bf16x8 af = *(const bf16x8*)&Wb[(mt*16+l16)*136 + k*32 + q*8];
            bf16x8 bf = *(const bf16x8*)&Xb[(pw+l16)*136 + k*32 + q*8];
            acc = MFMA16(af, bf, acc);
        }
        #pragma unroll
        for (int r=0;r<4;r++) hv[mt][r] = gelu_exact(acc[r] + bS[mt*16+q*4+r]);
    }
    #pragma unroll
    for (int mt=0;mt<8;mt++)
        #pragma unroll
        for (int r=0;r<4;r++)
            Xb[(pw+l16)*136 + mt*16+q*4+r] = f2bf(hv[mt][r]);
    __syncthreads();
    #pragma unroll
    for (int i=0;i<64;i++){ int idx=i*256+tid; Wb[(idx>>7)*136 + (idx&127)] = f2bf(w2[idx]); }
    __syncthreads();
    float* yb = xl2 + (size_t)b*CL*PL + hw0;
    #pragma unroll
    for (int mt=0; mt<8; mt++){
        f32x4 acc = {0.f,0.f,0.f,0.f};
        #pragma unroll
        for (int k=0;k<4;k++){
            bf16x8 af = *(const bf16x8*)&Wb[(mt*16+l16)*136 + k*32 + q*8];
            bf16x8 bf = *(const bf16x8*)&Xb[(pw+l16)*136 + k*32 + q*8];
            acc = MFMA16(af, bf, acc);
        }
        #pragma unroll
        for (int r=0;r<4;r++){
            int o = mt*16 + q*4 + r;
            size_t off = (size_t)o*PL + pw + l16;
            yb[off] = acc[r] + bS[128+o] + xb[off];
        }
    }
}

// ---------------- K2: xc = relu(bn(conv1x1(x_l2, conv_w)))  [MFMA bf16] ----------------
__global__ __launch_bounds__(256) void k_conv_l(
    const float* __restrict__ xl2, const float* __restrict__ cw,
    const float* __restrict__ bng, const float* __restrict__ bnb, float* __restrict__ xc)
{
    __shared__ short Wb[64*136];
    __shared__ short Xb[64*136];
    const int tid = threadIdx.x;
    const int b   = blockIdx.x / (PL/64);
    const int hw0 = (blockIdx.x % (PL/64)) * 64;
    const float* xb = xl2 + (size_t)b*CL*PL + hw0;
    #pragma unroll
    for (int i=0;i<32;i++){ int idx=i*256+tid; Wb[(idx>>7)*136 + (idx&127)] = f2bf(cw[idx]); }
    #pragma unroll
    for (int i=0;i<32;i++){ int idx=i*256+tid; int c=idx>>6, p=idx&63;
        Xb[p*136+c] = f2bf(xb[(size_t)c*PL + p]); }
    __syncthreads();
    const int w = tid>>6, lane = tid&63, l16 = lane&15, q = lane>>4;
    const int pw = w*16;
    float* yb = xc + (size_t)b*CH*PL + hw0;
    #pragma unroll
    for (int mt=0; mt<4; mt++){
        f32x4 acc = {0.f,0.f,0.f,0.f};
        #pragma unroll
        for (int k=0;k<4;k++){
            bf16x8 af = *(const bf16x8*)&Wb[(mt*16+l16)*136 + k*32 + q*8];
            bf16x8 bf = *(const bf16x8*)&Xb[(pw+l16)*136 + k*32 + q*8];
            acc = MFMA16(af, bf, acc);
        }
        #pragma unroll
        for (int r=0;r<4;r++){
            int o = mt*16 + q*4 + r;
            float sc = bng[o]*BN_S, bb = bnb[o];
            yb[(size_t)o*PL + pw + l16] = fmaxf(sc*acc[r] + bb, 0.f);
        }
    }
}

// ---------------- K3: x_h2 = x_h + bilinear_up2x(xc)  (half-pixel centers, edge clamp) ----------------
__global__ __launch_bounds__(256) void k_upsample_add(
    const float* __restrict__ xc, const float* __restrict__ xh, float* __restrict__ xh2)
{
    int gid = blockIdx.x*256 + threadIdx.x;
    int x = gid % WH;
    int r = gid / WH;
    int y = r % HH;
    int plane = r / HH;            // b*CH + c
    const float* s = xc + (size_t)plane*PL;
    int lx = (x>>1) - ((x&1)^1);
    float fx = (x&1) ? 0.25f : 0.75f;
    int x0i = lx<0?0:lx; int x1i = (lx+1>WL-1)?(WL-1):(lx+1);
    int ly = (y>>1) - ((y&1)^1);
    float fy = (y&1) ? 0.25f : 0.75f;
    int y0i = ly<0?0:ly; int y1i = (ly+1>HL-1)?(HL-1):(ly+1);
    float v00 = s[y0i*WL+x0i], v01 = s[y0i*WL+x1i];
    float v10 = s[y1i*WL+x0i], v11 = s[y1i*WL+x1i];
    float top = v00 + fx*(v01-v00);
    float bot = v10 + fx*(v11-v10);
    float up  = top + fy*(bot-top);
    xh2[gid] = xh[gid] + up;
}

// ---------------- K4a: pooled[b,c,s] = max_{8x8}( bn_kv(x_l2) ) ----------------
__global__ __launch_bounds__(192) void k_pool(
    const float* __restrict__ xl2, const float* __restrict__ g, const float* __restrict__ bta,
    float* __restrict__ pooled)
{
    const int plane = blockIdx.x;      // b*CL + c
    const int tid = threadIdx.x;
    if (tid >= NS) return;
    const int c = plane & (CL-1);
    const float sc = g[c]*BN_S;
    const float tc = bta[c];
    const int i = tid/12, j = tid%12;
    const float* base = xl2 + (size_t)plane*PL + (size_t)i*8*WL + j*8;
    float m = -3.4e38f;
    #pragma unroll
    for (int dy=0;dy<8;dy++){
        const float* rr = base + dy*WL;
        #pragma unroll
        for (int dx=0;dx<8;dx++) m = fmaxf(m, sc*rr[dx]+tc);
    }
    pooled[(size_t)plane*NS + tid] = m;
}

// ---------------- K4b: kv proj; K folded with norm-bn gamma + 1/12; V raw; bias term per slot -------
__global__ __launch_bounds__(512) void k_kv(
    const float* __restrict__ pooled, const float* __restrict__ kvw, const float* __restrict__ kvb,
    const float* __restrict__ ng, const float* __restrict__ nb,
    float* __restrict__ keg, float* __restrict__ vg, float* __restrict__ biasg)
{
    const int b = blockIdx.x;
    const int tid = threadIdx.x;
    const int o  = tid>>2;             // 0..127
    const int sq = (tid&3)*36;
    const float* P = pooled + (size_t)b*CL*NS + sq;
    float acc[36];
    float bb = kvb[o];
    #pragma unroll
    for (int s=0;s<36;s++) acc[s] = bb;
    for (int c=0;c<CL;c++){
        float w = kvw[o*CL+c];
        const float* Pr = P + c*NS;
        #pragma unroll
        for (int s=0;s<36;s++) acc[s] += w*Pr[s];
    }
    if (o < CH){
        float sn = ng[o]*(BN_S*INV12);
        float tn = nb[o]*INV12;
        #pragma unroll
        for (int s=0;s<36;s++){
            int ss = sq+s;
            keg[((size_t)b*NS+ss)*CH + o] = acc[s]*sn;
            atomicAdd(&biasg[b*NS+ss], acc[s]*tn);
        }
    } else {
        const int ch = o-CH;
        #pragma unroll
        for (int s=0;s<36;s++)
            vg[((size_t)b*NS+(sq+s))*CH + ch] = acc[s];
    }
}

// ---------------- K5: cross-attention [MFMA bf16, 64 px/block], out = xh2 + attn ----------------
// scores S[144x16/wave] = Ke[144x64] x X[64x16]; softmax in regs (shfl over quads);
// P -> LDS (bf16, transposed, padded to K=160); O[64x16] = Vt[64x160] x P[160x16]; scale by 1/sum.
__global__ __launch_bounds__(256) void k_attn(
    const float* __restrict__ xh2, const float* __restrict__ keg, const float* __restrict__ vg,
    const float* __restrict__ biasg, float* __restrict__ out)
{
    __shared__ short KVb[64*168];   // Ke (144x72) then Vt (64x168)
    __shared__ short Xb[64*72];     // Xt
    __shared__ short Pt[64*168];    // P transposed [p][s], K padded to 160
    __shared__ float bS[NS];
    const int tid = threadIdx.x;
    const int b   = blockIdx.x / (PH/64);
    const int hw0 = (blockIdx.x % (PH/64)) * 64;
    const float* xb = xh2 + (size_t)b*CH*PH + hw0;
    const float* keb = keg + (size_t)b*NS*CH;
    #pragma unroll
    for (int i=0;i<36;i++){ int idx=i*256+tid; KVb[(idx>>6)*72 + (idx&63)] = f2bf(keb[idx]); }
    #pragma unroll
    for (int i=0;i<16;i++){ int idx=i*256+tid; int c=idx>>6, p=idx&63;
        Xb[p*72+c] = f2bf(xb[(size_t)c*PH + p]); }
    if (tid < NS) bS[tid] = biasg[b*NS+tid];
    #pragma unroll
    for (int i=0;i<4;i++){ int idx=i*256+tid; Pt[(idx>>4)*168 + 144 + (idx&15)] = 0; }
    __syncthreads();
    const int w = tid>>6, lane = tid&63, l16 = lane&15, q = lane>>4;
    const int pw = w*16;
    float ev[9][4];
    float mloc = -3.4e38f;
    #pragma unroll
    for (int st=0; st<9; st++){
        f32x4 acc = {0.f,0.f,0.f,0.f};
        #pragma unroll
        for (int k=0;k<2;k++){
            bf16x8 af = *(const bf16x8*)&KVb[(st*16+l16)*72 + k*32 + q*8];
            bf16x8 bf = *(const bf16x8*)&Xb[(pw+l16)*72 + k*32 + q*8];
            acc = MFMA16(af, bf, acc);
        }
        #pragma unroll
        for (int r=0;r<4;r++){
            float v = acc[r] + bS[st*16+q*4+r];
            ev[st][r] = v; mloc = fmaxf(mloc, v);
        }
    }
    mloc = fmaxf(mloc, __shfl_xor(mloc,16));
    mloc = fmaxf(mloc, __shfl_xor(mloc,32));
    float sloc = 0.f;
    #pragma unroll
    for (int st=0;st<9;st++)
        #pragma unroll
        for (int r=0;r<4;r++){ float e = __expf(ev[st][r]-mloc); ev[st][r]=e; sloc+=e; }
    sloc += __shfl_xor(sloc,16);
    sloc += __shfl_xor(sloc,32);
    const float rs = 1.f/sloc;
    #pragma unroll
    for (int st=0;st<9;st++)
        #pragma unroll
        for (int r=0;r<4;r++)
            Pt[(pw+l16)*168 + st*16+q*4+r] = f2bf(ev[st][r]);
    __syncthreads();                       // Ke fully consumed; P visible
    const float* vb = vg + (size_t)b*NS*CH;
    #pragma unroll
    for (int i=0;i<36;i++){ int idx=i*256+tid; int s=idx>>6, c=idx&63;
        KVb[c*168 + s] = f2bf(vb[idx]); }
    #pragma unroll
    for (int i=0;i<4;i++){ int idx=i*256+tid; KVb[(idx>>4)*168 + 144 + (idx&15)] = 0; }
    __syncthreads();
    float* ob = out + (size_t)b*CH*PH + hw0;
    #pragma unroll
    for (int mt=0; mt<4; mt++){
        f32x4 acc = {0.f,0.f,0.f,0.f};
        #pragma unroll
        for (int k=0;k<5;k++){
            bf16x8 af = *(const bf16x8*)&KVb[(mt*16+l16)*168 + k*32 + q*8];
            bf16x8 bf = *(const bf16x8*)&Pt[(pw+l16)*168 + k*32 + q*8];
            acc = MFMA16(af, bf, acc);
        }
        #pragma unroll
        for (int r=0;r<4;r++){
            int ch = mt*16 + q*4 + r;
            size_t off = (size_t)ch*PH + pw + l16;
            ob[off] = xb[off] + acc[r]*rs;
        }
    }
}

// ---------------- K6: d_out += mlp_h(d_out)  [MFMA bf16, in-place] ----------------
__global__ __launch_bounds__(256) void k_mlp_h(
    float* __restrict__ xh, const float* __restrict__ w1, const float* __restrict__ b1,
    const float* __restrict__ w2, const float* __restrict__ b2)
{
    __shared__ short Wb[64*72];
    __shared__ short Xb[64*72];
    __shared__ float bS[128];
    const int tid = threadIdx.x;
    const int b   = blockIdx.x / (PH/64);
    const int hw0 = (blockIdx.x % (PH/64)) * 64;
    float* xb = xh + (size_t)b*CH*PH + hw0;
    #pragma unroll
    for (int i=0;i<16;i++){ int idx=i*256+tid; Wb[(idx>>6)*72 + (idx&63)] = f2bf(w1[idx]); }
    #pragma unroll
    for (int i=0;i<16;i++){ int idx=i*256+tid; int c=idx>>6, p=idx&63;
        Xb[p*72+c] = f2bf(xb[(size_t)c*PH + p]); }
    if (tid < 64) bS[tid] = b1[tid]; else if (tid < 128) bS[tid] = b2[tid-64];
    __syncthreads();
    const int w = tid>>6, lane = tid&63, l16 = lane&15, q = lane>>4;
    const int pw = w*16;
    float hv[4][4];
    #pragma unroll
    for (int mt=0; mt<4; mt++){
        f32x4 acc = {0.f,0.f,0.f,0.f};
        #pragma unroll
        for (int k=0;k<2;k++){
            bf16x8 af = *(const bf16x8*)&Wb[(mt*16+l16)*72 + k*32 + q*8];
            bf16x8 bf = *(const bf16x8*)&Xb[(pw+l16)*72 + k*32 + q*8];
            acc = MFMA16(af, bf, acc);
        }
        #pragma unroll
        for (int r=0;r<4;r++) hv[mt][r] = gelu_exact(acc[r] + bS[mt*16+q*4+r]);
    }
    #pragma unroll
    for (int mt=0;mt<4;mt++)
        #pragma unroll
        for (int r=0;r<4;r++)
            Xb[(pw+l16)*72 + mt*16+q*4+r] = f2bf(hv[mt][r]);
    __syncthreads();
    #pragma unroll
    for (int i=0;i<16;i++){ int idx=i*256+tid; Wb[(idx>>6)*72 + (idx&63)] = f2bf(w2[idx]); }
    __syncthreads();
    #pragma unroll
    for (int mt=0; mt<4; mt++){
        f32x4 acc = {0.f,0.f,0.f,0.f};
        #pragma unroll
        for (int k=0;k<2;k++){
            bf16x8 af = *(const bf16x8*)&Wb[(mt*16+l16)*72 + k*32 + q*8];
            bf16x8 bf = *(const bf16x8*)&Xb[(pw+l16)*72 + k*32 + q*8];
            acc = MFMA16(af, bf, acc);
        }
        #pragma unroll
        for (int r=0;r<4;r++){
            int o = mt*16 + q*4 + r;
            size_t off = (size_t)o*PH + pw + l16;
            xb[off] = acc[r] + bS[64+o] + xb[off];
        }
    }
}

extern "C" void kernel_launch(void* const* d_in, const int* in_sizes, int n_in,
                              void* d_out, int out_size, void* d_ws, size_t ws_size,
                              hipStream_t stream)
{
    const float* xl    = (const float*)d_in[0];
    const float* xh    = (const float*)d_in[1];
    const float* ml_w1 = (const float*)d_in[2];
    const float* ml_b1 = (const float*)d_in[3];
    const float* ml_w2 = (const float*)d_in[4];
    const float* ml_b2 = (const float*)d_in[5];
    const float* cw    = (const float*)d_in[6];
    const float* cbg   = (const float*)d_in[7];
    const float* cbb   = (const float*)d_in[8];
    const float* kbg   = (const float*)d_in[9];
    const float* kbb   = (const float*)d_in[10];
    const float* kvw   = (const float*)d_in[11];
    const float* kvb   = (const float*)d_in[12];
    const float* ng    = (const float*)d_in[13];
    const float* nb    = (const float*)d_in[14];
    const float* mh_w1 = (const float*)d_in[15];
    const float* mh_b1 = (const float*)d_in[16];
    const float* mh_w2 = (const float*)d_in[17];
    const float* mh_b2 = (const float*)d_in[18];
    float* out = (float*)d_out;

    float* ws     = (float*)d_ws;
    float* xl2    = ws;                          // NB*CL*PL
    float* xc     = xl2    + (size_t)NB*CL*PL;   // NB*CH*PL
    float* xh2    = xc     + (size_t)NB*CH*PL;   // NB*CH*PH
    float* pooled = xh2    + (size_t)NB*CH*PH;   // NB*CL*NS
    float* keg    = pooled + (size_t)NB*CL*NS;   // NB*NS*CH
    float* vg     = keg    + (size_t)NB*NS*CH;   // NB*NS*CH
    float* biasg  = vg     + (size_t)NB*NS*CH;   // NB*NS

    k_mlp_l<<<dim3(NB*PL/64), dim3(256), 0, stream>>>(xl, ml_w1, ml_b1, ml_w2, ml_b2, xl2);
    k_conv_l<<<dim3(NB*PL/64), dim3(256), 0, stream>>>(xl2, cw, cbg, cbb, xc);
    k_upsample_add<<<dim3((NB*CH*PH)/256), dim3(256), 0, stream>>>(xc, xh, xh2);
    k_pool<<<dim3(NB*CL), dim3(192), 0, stream>>>(xl2, kbg, kbb, pooled);
    hipMemsetAsync(biasg, 0, (size_t)NB*NS*sizeof(float), stream);
    k_kv<<<dim3(NB), dim3(512), 0, stream>>>(pooled, kvw, kvb, ng, nb, keg, vg, biasg);
    k_attn<<<dim3(NB*PH/64), dim3(256), 0, stream>>>(xh2, keg, vg, biasg, out);
    k_mlp_h<<<dim3(NB*PH/64), dim3(256), 0, stream>>>(out, mh_w1, mh_b1, mh_w2, mh_b2);
}

// Round 5
// 371.229 us; speedup vs baseline: 2.3293x; 1.3592x over previous
//
#include <hip/hip_runtime.h>
#include <math.h>

// Problem constants (fixed by reference: B=8, Cl=128, Ch=64, Hl=Wl=96, Hh=Wh=192, CROSS=12)
#define NB 8
#define CL 128
#define CH 64
#define HL 96
#define WL 96
#define PL (HL*WL)          // 9216
#define HH 192
#define WH 192
#define PH (HH*WH)          // 36864
#define NS 144              // CROSS*CROSS
#define BN_S 0.9999950000374997f   // 1/sqrt(1+1e-5)
#define INV12 (1.0f/12.0f)         // S^-0.5

typedef __attribute__((ext_vector_type(8))) short bf16x8;
typedef __attribute__((ext_vector_type(4))) float f32x4;
#define MFMA16(a,b,c) __builtin_amdgcn_mfma_f32_16x16x32_bf16(a,b,c,0,0,0)

__device__ __forceinline__ float gelu_exact(float x){
    return 0.5f*x*(1.0f + erff(x*0.7071067811865475f));
}
__device__ __forceinline__ short f2bf(float f){
    union { float f; unsigned u; } v; v.f = f;
    unsigned r = v.u + 0x7FFFu + ((v.u >> 16) & 1u);   // round-nearest-even
    return (short)(r >> 16);
}

// ---------------- K1: x_l2 = x_l + mlp_l(x_l)  [MFMA bf16, 64 px/block, 4 waves x 16 px] ----------
__global__ __launch_bounds__(256) void k_mlp_l(
    const float* __restrict__ xl, const float* __restrict__ w1, const float* __restrict__ b1,
    const float* __restrict__ w2, const float* __restrict__ b2, float* __restrict__ xl2)
{
    __shared__ short Wb[128*136];   // W1 then W2
    __shared__ short Xb[64*136];    // Xt then Ht
    __shared__ float bS[256];       // b1 | b2
    const int tid = threadIdx.x;
    const int b   = blockIdx.x / (PL/64);
    const int hw0 = (blockIdx.x % (PL/64)) * 64;
    const float* xb = xl + (size_t)b*CL*PL + hw0;
    #pragma unroll
    for (int i=0;i<64;i++){ int idx=i*256+tid; Wb[(idx>>7)*136 + (idx&127)] = f2bf(w1[idx]); }
    #pragma unroll
    for (int i=0;i<32;i++){ int idx=i*256+tid; int c=idx>>6, p=idx&63;
        Xb[p*136+c] = f2bf(xb[(size_t)c*PL + p]); }
    if (tid < 128) bS[tid] = b1[tid]; else bS[tid] = b2[tid-128];
    __syncthreads();
    const int w = tid>>6, lane = tid&63, l16 = lane&15, q = lane>>4;
    const int pw = w*16;
    float hv[8][4];
    #pragma unroll
    for (int mt=0; mt<8; mt++){
        f32x4 acc = {0.f,0.f,0.f,0.f};
        #pragma unroll
        for (int k=0;k<4;k++){
            bf16x8 af = *(const bf16x8*)&Wb[(mt*16+l16)*136 + k*32 + q*8];
            bf16x8 bf = *(const bf16x8*)&Xb[(pw+l16)*136 + k*32 + q*8];
            acc = MFMA16(af, bf, acc);
        }
        #pragma unroll
        for (int r=0;r<4;r++) hv[mt][r] = gelu_exact(acc[r] + bS[mt*16+q*4+r]);
    }
    #pragma unroll
    for (int mt=0;mt<8;mt++)
        #pragma unroll
        for (int r=0;r<4;r++)
            Xb[(pw+l16)*136 + mt*16+q*4+r] = f2bf(hv[mt][r]);
    __syncthreads();
    #pragma unroll
    for (int i=0;i<64;i++){ int idx=i*256+tid; Wb[(idx>>7)*136 + (idx&127)] = f2bf(w2[idx]); }
    __syncthreads();
    float* yb = xl2 + (size_t)b*CL*PL + hw0;
    #pragma unroll
    for (int mt=0; mt<8; mt++){
        f32x4 acc = {0.f,0.f,0.f,0.f};
        #pragma unroll
        for (int k=0;k<4;k++){
            bf16x8 af = *(const bf16x8*)&Wb[(mt*16+l16)*136 + k*32 + q*8];
            bf16x8 bf = *(const bf16x8*)&Xb[(pw+l16)*136 + k*32 + q*8];
            acc = MFMA16(af, bf, acc);
        }
        #pragma unroll
        for (int r=0;r<4;r++){
            int o = mt*16 + q*4 + r;
            size_t off = (size_t)o*PL + pw + l16;
            yb[off] = acc[r] + bS[128+o] + xb[off];
        }
    }
}

// ---------------- K2: xc = relu(bn(conv1x1(x_l2, conv_w)))  [MFMA bf16] ----------------
__global__ __launch_bounds__(256) void k_conv_l(
    const float* __restrict__ xl2, const float* __restrict__ cw,
    const float* __restrict__ bng, const float* __restrict__ bnb, float* __restrict__ xc)
{
    __shared__ short Wb[64*136];
    __shared__ short Xb[64*136];
    const int tid = threadIdx.x;
    const int b   = blockIdx.x / (PL/64);
    const int hw0 = (blockIdx.x % (PL/64)) * 64;
    const float* xb = xl2 + (size_t)b*CL*PL + hw0;
    #pragma unroll
    for (int i=0;i<32;i++){ int idx=i*256+tid; Wb[(idx>>7)*136 + (idx&127)] = f2bf(cw[idx]); }
    #pragma unroll
    for (int i=0;i<32;i++){ int idx=i*256+tid; int c=idx>>6, p=idx&63;
        Xb[p*136+c] = f2bf(xb[(size_t)c*PL + p]); }
    __syncthreads();
    const int w = tid>>6, lane = tid&63, l16 = lane&15, q = lane>>4;
    const int pw = w*16;
    float* yb = xc + (size_t)b*CH*PL + hw0;
    #pragma unroll
    for (int mt=0; mt<4; mt++){
        f32x4 acc = {0.f,0.f,0.f,0.f};
        #pragma unroll
        for (int k=0;k<4;k++){
            bf16x8 af = *(const bf16x8*)&Wb[(mt*16+l16)*136 + k*32 + q*8];
            bf16x8 bf = *(const bf16x8*)&Xb[(pw+l16)*136 + k*32 + q*8];
            acc = MFMA16(af, bf, acc);
        }
        #pragma unroll
        for (int r=0;r<4;r++){
            int o = mt*16 + q*4 + r;
            float sc = bng[o]*BN_S, bb = bnb[o];
            yb[(size_t)o*PL + pw + l16] = fmaxf(sc*acc[r] + bb, 0.f);
        }
    }
}

// ---------------- K3: x_h2 = x_h + bilinear_up2x(xc)  (half-pixel centers, edge clamp) ----------------
__global__ __launch_bounds__(256) void k_upsample_add(
    const float* __restrict__ xc, const float* __restrict__ xh, float* __restrict__ xh2)
{
    int gid = blockIdx.x*256 + threadIdx.x;
    int x = gid % WH;
    int r = gid / WH;
    int y = r % HH;
    int plane = r / HH;            // b*CH + c
    const float* s = xc + (size_t)plane*PL;
    int lx = (x>>1) - ((x&1)^1);
    float fx = (x&1) ? 0.25f : 0.75f;
    int x0i = lx<0?0:lx; int x1i = (lx+1>WL-1)?(WL-1):(lx+1);
    int ly = (y>>1) - ((y&1)^1);
    float fy = (y&1) ? 0.25f : 0.75f;
    int y0i = ly<0?0:ly; int y1i = (ly+1>HL-1)?(HL-1):(ly+1);
    float v00 = s[y0i*WL+x0i], v01 = s[y0i*WL+x1i];
    float v10 = s[y1i*WL+x0i], v11 = s[y1i*WL+x1i];
    float top = v00 + fx*(v01-v00);
    float bot = v10 + fx*(v11-v10);
    float up  = top + fy*(bot-top);
    xh2[gid] = xh[gid] + up;
}

// ---------------- K4a: pooled[b,c,s] = max_{8x8}( bn_kv(x_l2) ) ----------------
__global__ __launch_bounds__(192) void k_pool(
    const float* __restrict__ xl2, const float* __restrict__ g, const float* __restrict__ bta,
    float* __restrict__ pooled)
{
    const int plane = blockIdx.x;      // b*CL + c
    const int tid = threadIdx.x;
    if (tid >= NS) return;
    const int c = plane & (CL-1);
    const float sc = g[c]*BN_S;
    const float tc = bta[c];
    const int i = tid/12, j = tid%12;
    const float* base = xl2 + (size_t)plane*PL + (size_t)i*8*WL + j*8;
    float m = -3.4e38f;
    #pragma unroll
    for (int dy=0;dy<8;dy++){
        const float* rr = base + dy*WL;
        #pragma unroll
        for (int dx=0;dx<8;dx++) m = fmaxf(m, sc*rr[dx]+tc);
    }
    pooled[(size_t)plane*NS + tid] = m;
}

// ---------------- K4b: kv proj, thread per (o,s), o in 0..127 (2*Ch=128 rows): 576 blocks --------
// keg[b][s][ch] = kv_k * ng[ch]*BN_S/12 ; biasg[b][s] += kv_k * nb[ch]/12 ; vg[b][s][ch] = kv_v
__global__ __launch_bounds__(256) void k_kv(
    const float* __restrict__ pooled, const float* __restrict__ kvw, const float* __restrict__ kvb,
    const float* __restrict__ ng, const float* __restrict__ nb,
    float* __restrict__ keg, float* __restrict__ vg, float* __restrict__ biasg)
{
    const int t = blockIdx.x*256 + threadIdx.x;     // over NB*128*NS = 147456
    const int s = t % NS;
    const int r = t / NS;
    const int o = r & 127;        // 2*Ch = 128 output rows
    const int b = r >> 7;
    const float* P = pooled + (size_t)b*CL*NS + s;
    const float* W = kvw + (size_t)o*CL;
    float acc = kvb[o];
    #pragma unroll 4
    for (int c=0;c<CL;c++) acc = fmaf(W[c], P[(size_t)c*NS], acc);
    if (o < CH){
        keg[((size_t)b*NS+s)*CH + o] = acc * (ng[o]*(BN_S*INV12));
        atomicAdd(&biasg[b*NS+s], acc * (nb[o]*INV12));
    } else {
        vg[((size_t)b*NS+s)*CH + (o-CH)] = acc;
    }
}

// ---------------- K5: cross-attention [MFMA bf16, 64 px/block], out = xh2 + attn ----------------
__global__ __launch_bounds__(256) void k_attn(
    const float* __restrict__ xh2, const float* __restrict__ keg, const float* __restrict__ vg,
    const float* __restrict__ biasg, float* __restrict__ out)
{
    __shared__ short KVb[64*168];   // Ke (144x72) then Vt (64x168)
    __shared__ short Xb[64*72];     // Xt
    __shared__ short Pt[64*168];    // P transposed [p][s], K padded to 160
    __shared__ float bS[NS];
    const int tid = threadIdx.x;
    const int b   = blockIdx.x / (PH/64);
    const int hw0 = (blockIdx.x % (PH/64)) * 64;
    const float* xb = xh2 + (size_t)b*CH*PH + hw0;
    const float* keb = keg + (size_t)b*NS*CH;
    #pragma unroll
    for (int i=0;i<36;i++){ int idx=i*256+tid; KVb[(idx>>6)*72 + (idx&63)] = f2bf(keb[idx]); }
    #pragma unroll
    for (int i=0;i<16;i++){ int idx=i*256+tid; int c=idx>>6, p=idx&63;
        Xb[p*72+c] = f2bf(xb[(size_t)c*PH + p]); }
    if (tid < NS) bS[tid] = biasg[b*NS+tid];
    #pragma unroll
    for (int i=0;i<4;i++){ int idx=i*256+tid; Pt[(idx>>4)*168 + 144 + (idx&15)] = 0; }
    __syncthreads();
    const int w = tid>>6, lane = tid&63, l16 = lane&15, q = lane>>4;
    const int pw = w*16;
    float ev[9][4];
    float mloc = -3.4e38f;
    #pragma unroll
    for (int st=0; st<9; st++){
        f32x4 acc = {0.f,0.f,0.f,0.f};
        #pragma unroll
        for (int k=0;k<2;k++){
            bf16x8 af = *(const bf16x8*)&KVb[(st*16+l16)*72 + k*32 + q*8];
            bf16x8 bf = *(const bf16x8*)&Xb[(pw+l16)*72 + k*32 + q*8];
            acc = MFMA16(af, bf, acc);
        }
        #pragma unroll
        for (int r=0;r<4;r++){
            float v = acc[r] + bS[st*16+q*4+r];
            ev[st][r] = v; mloc = fmaxf(mloc, v);
        }
    }
    mloc = fmaxf(mloc, __shfl_xor(mloc,16));
    mloc = fmaxf(mloc, __shfl_xor(mloc,32));
    float sloc = 0.f;
    #pragma unroll
    for (int st=0;st<9;st++)
        #pragma unroll
        for (int r=0;r<4;r++){ float e = __expf(ev[st][r]-mloc); ev[st][r]=e; sloc+=e; }
    sloc += __shfl_xor(sloc,16);
    sloc += __shfl_xor(sloc,32);
    const float rs = 1.f/sloc;
    #pragma unroll
    for (int st=0;st<9;st++)
        #pragma unroll
        for (int r=0;r<4;r++)
            Pt[(pw+l16)*168 + st*16+q*4+r] = f2bf(ev[st][r]);
    __syncthreads();                       // Ke fully consumed; P visible
    const float* vb = vg + (size_t)b*NS*CH;
    #pragma unroll
    for (int i=0;i<36;i++){ int idx=i*256+tid; int s=idx>>6, c=idx&63;
        KVb[c*168 + s] = f2bf(vb[idx]); }
    #pragma unroll
    for (int i=0;i<4;i++){ int idx=i*256+tid; KVb[(idx>>4)*168 + 144 + (idx&15)] = 0; }
    __syncthreads();
    float* ob = out + (size_t)b*CH*PH + hw0;
    #pragma unroll
    for (int mt=0; mt<4; mt++){
        f32x4 acc = {0.f,0.f,0.f,0.f};
        #pragma unroll
        for (int k=0;k<5;k++){
            bf16x8 af = *(const bf16x8*)&KVb[(mt*16+l16)*168 + k*32 + q*8];
            bf16x8 bf = *(const bf16x8*)&Pt[(pw+l16)*168 + k*32 + q*8];
            acc = MFMA16(af, bf, acc);
        }
        #pragma unroll
        for (int r=0;r<4;r++){
            int ch = mt*16 + q*4 + r;
            size_t off = (size_t)ch*PH + pw + l16;
            ob[off] = xb[off] + acc[r]*rs;
        }
    }
}

// ---------------- K6: d_out += mlp_h(d_out)  [MFMA bf16, in-place] ----------------
__global__ __launch_bounds__(256) void k_mlp_h(
    float* __restrict__ xh, const float* __restrict__ w1, const float* __restrict__ b1,
    const float* __restrict__ w2, const float* __restrict__ b2)
{
    __shared__ short Wb[64*72];
    __shared__ short Xb[64*72];
    __shared__ float bS[128];
    const int tid = threadIdx.x;
    const int b   = blockIdx.x / (PH/64);
    const int hw0 = (blockIdx.x % (PH/64)) * 64;
    float* xb = xh + (size_t)b*CH*PH + hw0;
    #pragma unroll
    for (int i=0;i<16;i++){ int idx=i*256+tid; Wb[(idx>>6)*72 + (idx&63)] = f2bf(w1[idx]); }
    #pragma unroll
    for (int i=0;i<16;i++){ int idx=i*256+tid; int c=idx>>6, p=idx&63;
        Xb[p*72+c] = f2bf(xb[(size_t)c*PH + p]); }
    if (tid < 64) bS[tid] = b1[tid]; else if (tid < 128) bS[tid] = b2[tid-64];
    __syncthreads();
    const int w = tid>>6, lane = tid&63, l16 = lane&15, q = lane>>4;
    const int pw = w*16;
    float hv[4][4];
    #pragma unroll
    for (int mt=0; mt<4; mt++){
        f32x4 acc = {0.f,0.f,0.f,0.f};
        #pragma unroll
        for (int k=0;k<2;k++){
            bf16x8 af = *(const bf16x8*)&Wb[(mt*16+l16)*72 + k*32 + q*8];
            bf16x8 bf = *(const bf16x8*)&Xb[(pw+l16)*72 + k*32 + q*8];
            acc = MFMA16(af, bf, acc);
        }
        #pragma unroll
        for (int r=0;r<4;r++) hv[mt][r] = gelu_exact(acc[r] + bS[mt*16+q*4+r]);
    }
    #pragma unroll
    for (int mt=0;mt<4;mt++)
        #pragma unroll
        for (int r=0;r<4;r++)
            Xb[(pw+l16)*72 + mt*16+q*4+r] = f2bf(hv[mt][r]);
    __syncthreads();
    #pragma unroll
    for (int i=0;i<16;i++){ int idx=i*256+tid; Wb[(idx>>6)*72 + (idx&63)] = f2bf(w2[idx]); }
    __syncthreads();
    #pragma unroll
    for (int mt=0; mt<4; mt++){
        f32x4 acc = {0.f,0.f,0.f,0.f};
        #pragma unroll
        for (int k=0;k<2;k++){
            bf16x8 af = *(const bf16x8*)&Wb[(mt*16+l16)*72 + k*32 + q*8];
            bf16x8 bf = *(const bf16x8*)&Xb[(pw+l16)*72 + k*32 + q*8];
            acc = MFMA16(af, bf, acc);
        }
        #pragma unroll
        for (int r=0;r<4;r++){
            int o = mt*16 + q*4 + r;
            size_t off = (size_t)o*PH + pw + l16;
            xb[off] = acc[r] + bS[64+o] + xb[off];
        }
    }
}

extern "C" void kernel_launch(void* const* d_in, const int* in_sizes, int n_in,
                              void* d_out, int out_size, void* d_ws, size_t ws_size,
                              hipStream_t stream)
{
    const float* xl    = (const float*)d_in[0];
    const float* xh    = (const float*)d_in[1];
    const float* ml_w1 = (const float*)d_in[2];
    const float* ml_b1 = (const float*)d_in[3];
    const float* ml_w2 = (const float*)d_in[4];
    const float* ml_b2 = (const float*)d_in[5];
    const float* cw    = (const float*)d_in[6];
    const float* cbg   = (const float*)d_in[7];
    const float* cbb   = (const float*)d_in[8];
    const float* kbg   = (const float*)d_in[9];
    const float* kbb   = (const float*)d_in[10];
    const float* kvw   = (const float*)d_in[11];
    const float* kvb   = (const float*)d_in[12];
    const float* ng    = (const float*)d_in[13];
    const float* nb    = (const float*)d_in[14];
    const float* mh_w1 = (const float*)d_in[15];
    const float* mh_b1 = (const float*)d_in[16];
    const float* mh_w2 = (const float*)d_in[17];
    const float* mh_b2 = (const float*)d_in[18];
    float* out = (float*)d_out;

    float* ws     = (float*)d_ws;
    float* xl2    = ws;                          // NB*CL*PL
    float* xc     = xl2    + (size_t)NB*CL*PL;   // NB*CH*PL
    float* xh2    = xc     + (size_t)NB*CH*PL;   // NB*CH*PH
    float* pooled = xh2    + (size_t)NB*CH*PH;   // NB*CL*NS
    float* keg    = pooled + (size_t)NB*CL*NS;   // NB*NS*CH
    float* vg     = keg    + (size_t)NB*NS*CH;   // NB*NS*CH
    float* biasg  = vg     + (size_t)NB*NS*CH;   // NB*NS

    k_mlp_l<<<dim3(NB*PL/64), dim3(256), 0, stream>>>(xl, ml_w1, ml_b1, ml_w2, ml_b2, xl2);
    k_conv_l<<<dim3(NB*PL/64), dim3(256), 0, stream>>>(xl2, cw, cbg, cbb, xc);
    k_upsample_add<<<dim3((NB*CH*PH)/256), dim3(256), 0, stream>>>(xc, xh, xh2);
    k_pool<<<dim3(NB*CL), dim3(192), 0, stream>>>(xl2, kbg, kbb, pooled);
    hipMemsetAsync(biasg, 0, (size_t)NB*NS*sizeof(float), stream);
    k_kv<<<dim3((NB*128*NS)/256), dim3(256), 0, stream>>>(pooled, kvw, kvb, ng, nb, keg, vg, biasg);
    k_attn<<<dim3(NB*PH/64), dim3(256), 0, stream>>>(xh2, keg, vg, biasg, out);
    k_mlp_h<<<dim3(NB*PH/64), dim3(256), 0, stream>>>(out, mh_w1, mh_b1, mh_w2, mh_b2);
}